// Round 14
// baseline (228.104 us; speedup 1.0000x reference)
//
#include <hip/hip_runtime.h>

typedef _Float16 hf;
typedef _Float16 half2v __attribute__((ext_vector_type(2)));
typedef _Float16 half4 __attribute__((ext_vector_type(4)));
typedef _Float16 half8 __attribute__((ext_vector_type(8)));
typedef float f32x4 __attribute__((ext_vector_type(4)));
typedef int int4v __attribute__((ext_vector_type(4)));

constexpr int Steps = 27;

// wsh half-index layout (prep output), PLUS xWb at OFF_XW (written by witran prologue):
//   wrec : [0, 393216)         (((cls*16+wv16)*3+j)*8+ks)*512 + lane*8 + jj
//   wx   : [393216, 589824)    (((cls*6+g)*8+wv)*4+ks)*512 + lane*8 + j   K=[256,384)
//   fc3  : [589824, 598016)
//   fc4  : [598016, 614400)
//   xWb  : [614400, +18874368)  [cls][bn][cell][d*6+pos], pos 0,1,2=u_r,o_r,i_r; 3,4,5=u_c,o_c,i_c
constexpr int OFF_WX = 393216;
constexpr int OFF_F3 = 589824;
constexpr int OFF_F4 = 598016;
constexpr int OFF_XW = 614400;

// witran smem (halfs), time-shared:
//   prologue: [0,12288) xA | [12288,36864) h1 | [36864,61440) h   then chunks: [0,36864) xout
//   recurrence: [0,4096) A0 | [4096,8192) A1 | [8192,40960) wlds  (h region dead)
constexpr int XA_OFF = 0;
constexpr int H1_OFF = 12288;
constexpr int H_OFF = 36864;
constexpr int XOUT_OFF = 0;
constexpr int A0_OFF = 0;
constexpr int A1_OFF = 4096;
constexpr int WL_OFF = 8192;
constexpr int SM_HALFS = 61440;  // 122880 B

__device__ __forceinline__ int aidx(int r, int k) {  // halfs, K=256 (witran A)
  int blk = k >> 3;
  return r * 256 + (((blk ^ (r & 7)) & 31) << 3) + (k & 7);
}
__device__ __forceinline__ int hidx(int r, int k) {  // halfs, K=128 (h buffers)
  int blk = k >> 3;
  return r * 128 + (((blk ^ (r & 15)) & 15) << 3) + (k & 7);
}
__device__ __forceinline__ int xidx(int r, int k) {  // halfs, K=64 (x staging)
  int blk = k >> 3;
  return r * 64 + (((blk ^ (r & 7)) & 7) << 3) + (k & 7);
}
__device__ __forceinline__ float rcpf_(float x) { return __builtin_amdgcn_rcpf(x); }
__device__ __forceinline__ float sigmoidf_(float x) { return rcpf_(1.0f + __expf(-x)); }
__device__ __forceinline__ float tanh_(float x) { return 1.0f - 2.0f * rcpf_(__expf(2.0f * x) + 1.0f); }

// Hardened lgkm-only barrier (R12-proven): SGPR zero produced by the barrier asm;
// post-barrier LDS pointers offset by it (data dep = no hoisting). No "memory"
// clobber -> no vmcnt drain (R9's -12us).
__device__ __forceinline__ int bar_dep() {
  int z;
  __builtin_amdgcn_sched_barrier(0);
  asm volatile("s_waitcnt lgkmcnt(0)\n\ts_barrier\n\ts_mov_b32 %0, 0" : "=s"(z));
  __builtin_amdgcn_sched_barrier(0);
  return z;
}

// ---- kernel 1: all weights -> fragment-ordered fp16 (R12 verbatim) ----
__global__ __launch_bounds__(512) void prep(const float* __restrict__ fc3_w,
                                            const float* __restrict__ fc4_w,
                                            const float* __restrict__ W_enc,
                                            hf* __restrict__ wsh) {
  int idx = (blockIdx.x * 512 + threadIdx.x) * 8;  // base of 8-chunk
  if (idx >= OFF_XW) return;
  const float* src;
  if (idx < OFF_WX) {  // recurrent W, gate-triple per wave-block
    int lane = (idx >> 3) & 63, rest = idx >> 9;
    int ks = rest & 7; rest >>= 3;
    int j = rest % 3; rest /= 3;
    int wv = rest & 15, cls = rest >> 4;
    int gate = (wv < 8) ? (j < 2 ? j : 4) : (j < 2 ? j + 2 : 5);  // {0,1,4} / {2,3,5}
    int n = gate * 128 + (wv & 7) * 16 + (lane & 15);
    int k = ks * 32 + ((lane >> 4) << 3);
    src = W_enc + (size_t)(cls * 768 + n) * 384 + k;
  } else if (idx < OFF_F3) {  // x-part Wx
    int f = idx - OFF_WX;
    int lane = (f >> 3) & 63, rest = f >> 9;
    int ks = rest & 3; rest >>= 2;
    int wv = rest & 7; rest >>= 3;
    int gate = rest % 6, cls = rest / 6;
    int n = gate * 128 + wv * 16 + (lane & 15);
    int k = 256 + ks * 32 + ((lane >> 4) << 3);
    src = W_enc + (size_t)(cls * 768 + n) * 384 + k;
  } else if (idx < OFF_F4) {  // fc3
    int f = idx - OFF_F3;
    int lane = (f >> 3) & 63, rest = f >> 9;
    int ks = rest & 1, wv = rest >> 1;
    int n = wv * 16 + (lane & 15), k = ks * 32 + ((lane >> 4) << 3);
    src = fc3_w + n * 64 + k;
  } else {  // fc4
    int f = idx - OFF_F4;
    int lane = (f >> 3) & 63, rest = f >> 9;
    int ks = rest & 3, wv = rest >> 2;
    int n = wv * 16 + (lane & 15), k = ks * 32 + ((lane >> 4) << 3);
    src = fc4_w + n * 128 + k;
  }
  f32x4 a = *(const f32x4*)src, b = *(const f32x4*)(src + 4);
  half8 h;
  h[0] = (hf)a.x; h[1] = (hf)a.y; h[2] = (hf)a.z; h[3] = (hf)a.w;
  h[4] = (hf)b.x; h[5] = (hf)b.y; h[6] = (hf)b.z; h[7] = (hf)b.w;
  *(half8*)&wsh[idx] = h;
}

__device__ __forceinline__ float lo16f(unsigned v) {
  return (float)__builtin_bit_cast(half2v, v)[0];
}
__device__ __forceinline__ float hi16f(unsigned v) {
  return (float)__builtin_bit_cast(half2v, v)[1];
}

// ---- kernel 2: FUSED. Prologue = old prelude for THIS (cls,bn): fc3+fc4 -> h in LDS,
// then xW in 4 row-chunks (LDS xout staging, coalesced store to own xWb slice in ws).
// NOT in the step loop (R13's mistake). Then __threadfence (writes->L2, L1 inval) and
// the R12-VERBATIM recurrence reads the slice back (L2-resident, prefetched, okx-at-use).
// Removes the prelude kernel + drain boundary (R13 measured: 2-launch tail 68us vs 100).
__global__ __launch_bounds__(512, 2) __attribute__((amdgpu_waves_per_eu(2, 2))) void witran(
    const hf* __restrict__ wsh, hf* __restrict__ xWb, const float* __restrict__ x,
    const float* __restrict__ fc3_b, const float* __restrict__ fc4_b,
    const float* __restrict__ B_enc,
    const float* __restrict__ fc1_w, const float* __restrict__ fc1_b,
    const float* __restrict__ fc2_w, const float* __restrict__ fc2_b,
    float* __restrict__ out) {
  const int cls = blockIdx.x & 1, bn = blockIdx.x >> 1;
  const int t = threadIdx.x, lane = t & 63, wv = t >> 6;  // wv 0..7
  const int c16 = lane & 15, quad = lane >> 4;
  const int d = wv * 16 + c16;
  const bool act = (quad < 3);
  const int c0 = quad * 4;

  __shared__ __attribute__((aligned(16))) hf smem[SM_HALFS];

  // resident recurrent weights (R12 config): wf[0..2]=u_r,o_r,i_r; wf[3..4]=u_c,o_c;
  // i_c -> wlds (staged after prologue)
  half8 wf[5][8];
  {
    const hf* wbR = wsh + ((size_t)((cls * 16 + wv) * 3) * 8) * 512 + lane * 8;
    const hf* wbC = wsh + ((size_t)((cls * 16 + 8 + wv) * 3) * 8) * 512 + lane * 8;
#pragma unroll
    for (int j = 0; j < 3; ++j)
#pragma unroll
      for (int ks = 0; ks < 8; ++ks)
        wf[j][ks] = *(const half8*)(wbR + (j * 8 + ks) * 512);
#pragma unroll
    for (int j = 0; j < 2; ++j)
#pragma unroll
      for (int ks = 0; ks < 8; ++ks)
        wf[3 + j][ks] = *(const half8*)(wbC + (j * 8 + ks) * 512);
  }

  hf* xg = xWb + ((size_t)cls * 64 + bn) * 192 * 768;  // this block's slice

  // ---- prologue 1: stage x -> fp16 LDS (192 rows x 64; R13-proven) ----
#pragma unroll
  for (int i = 0; i < 6; ++i) {
    int f = t * 4 + i * 2048;
    int r = f >> 6, cb = f & 63;
    f32x4 a = *(const f32x4*)(x + (size_t)(bn * 192 + r) * 64 + cb);
    half4 h4;
    h4[0] = (hf)a.x; h4[1] = (hf)a.y; h4[2] = (hf)a.z; h4[3] = (hf)a.w;
    *(half4*)&smem[XA_OFF + xidx(r, cb)] = h4;  // cb&7 in {0,4}: inside one 8-unit
  }
  __syncthreads();

  // fc3: xA -> h1 (M=192, K=64) [R13-proven]
  {
    float b3v = fc3_b[d];
    half8 w0 = *(const half8*)(wsh + OFF_F3 + (wv * 2 + 0) * 512 + lane * 8);
    half8 w1 = *(const half8*)(wsh + OFF_F3 + (wv * 2 + 1) * 512 + lane * 8);
#pragma unroll
    for (int mt = 0; mt < 12; ++mt) {
      f32x4 a = {0.f, 0.f, 0.f, 0.f};
      a = __builtin_amdgcn_mfma_f32_16x16x32_f16(
          *(const half8*)&smem[XA_OFF + xidx(mt * 16 + c16, quad * 8)], w0, a, 0, 0, 0);
      a = __builtin_amdgcn_mfma_f32_16x16x32_f16(
          *(const half8*)&smem[XA_OFF + xidx(mt * 16 + c16, 32 + quad * 8)], w1, a, 0, 0, 0);
#pragma unroll
      for (int r = 0; r < 4; ++r)
        smem[H1_OFF + hidx(mt * 16 + quad * 4 + r, d)] = (hf)fmaxf(a[r] + b3v, 0.f);
    }
  }
  __syncthreads();

  // fc4: h1 -> h (M=192, K=128) [R13-proven]
  {
    float b4v = fc4_b[d];
    half8 w4[4];
#pragma unroll
    for (int ks = 0; ks < 4; ++ks)
      w4[ks] = *(const half8*)(wsh + OFF_F4 + (wv * 4 + ks) * 512 + lane * 8);
#pragma unroll
    for (int mt = 0; mt < 12; ++mt) {
      f32x4 a = {0.f, 0.f, 0.f, 0.f};
#pragma unroll
      for (int ks = 0; ks < 4; ++ks)
        a = __builtin_amdgcn_mfma_f32_16x16x32_f16(
            *(const half8*)&smem[H1_OFF + hidx(mt * 16 + c16, ks * 32 + quad * 8)], w4[ks], a,
            0, 0, 0);
#pragma unroll
      for (int r = 0; r < 4; ++r)
        smem[H_OFF + hidx(mt * 16 + quad * 4 + r, d)] = (hf)(a[r] + b4v);
    }
  }
  __syncthreads();  // xA/h1 dead -> xout region free

  // ---- prologue 2: xW in 4 chunks of 48 rows; xout staging + coalesced store
  // (prelude-proven pattern, retargeted to this block's slice) ----
  for (int cc = 0; cc < 4; ++cc) {
    half8 af_c[3][4];
#pragma unroll
    for (int ml = 0; ml < 3; ++ml)
#pragma unroll
      for (int ks = 0; ks < 4; ++ks)
        af_c[ml][ks] =
            *(const half8*)&smem[H_OFF + hidx((cc * 3 + ml) * 16 + c16, ks * 32 + quad * 8)];
    for (int g = 0; g < 6; ++g) {
      int pos = (g < 2) ? g : (g < 4 ? g + 1 : (g == 4 ? 2 : 5));
      half8 wfk[4];
#pragma unroll
      for (int ks = 0; ks < 4; ++ks)
        wfk[ks] = *(const half8*)(wsh + OFF_WX + (((cls * 6 + g) * 8 + wv) * 4 + ks) * 512 + lane * 8);
      float bv = B_enc[cls * 768 + g * 128 + d];
#pragma unroll
      for (int ml = 0; ml < 3; ++ml) {
        f32x4 a = {0.f, 0.f, 0.f, 0.f};
#pragma unroll
        for (int ks = 0; ks < 4; ++ks)
          a = __builtin_amdgcn_mfma_f32_16x16x32_f16(af_c[ml][ks], wfk[ks], a, 0, 0, 0);
#pragma unroll
        for (int r = 0; r < 4; ++r) {
          int lrow = ml * 16 + quad * 4 + r;        // row within chunk
          int row = cc * 48 + lrow;                 // cell index 0..191
          float actf = ((row / 12) + (row % 12)) < 12 ? 1.f : 0.f;
          smem[XOUT_OFF + lrow * 768 + d * 6 + pos] = (hf)(a[r] + actf * bv);
        }
      }
    }
    __syncthreads();  // xout chunk complete
    {
      const int* src = (const int*)&smem[XOUT_OFF];
      int* dst = (int*)(xg + (size_t)cc * 48 * 768);
#pragma unroll
      for (int i = 0; i < 9; ++i) {
        int base = (t + i * 512) * 4;
        *(int4v*)&dst[base] = *(const int4v*)&src[base];
      }
    }
    __syncthreads();  // copy done before xout reuse
  }

  __threadfence();  // one-time: drain stores to L2, invalidate L1 (own-slice readback)

  // ---- recurrence setup: zero A dbuf, stage i_c into wlds ----
  for (int i = t; i < 4096; i += 512) ((int*)&smem[A0_OFF])[i] = 0;
  {
    const hf* wbC = wsh + ((size_t)((cls * 16 + 8 + wv) * 3) * 8) * 512 + lane * 8;
#pragma unroll
    for (int ks = 0; ks < 8; ++ks)
      *(half8*)&smem[WL_OFF + wv * 4096 + ks * 512 + lane * 8] =
          *(const half8*)(wbC + (16 + ks) * 512);
  }

  // x byte-offset (R12 verbatim): off(s,c) = s*18432 - c*16896 + d*12
  int xrun = d * 12 - c0 * 16896;
  unsigned pxc[4][3];
  float hr[4] = {0.f, 0.f, 0.f, 0.f};  // row holds: registers

  auto xload = [&](int s) {  // prefetch x-gates for step s; RAW values, no select on data
#pragma unroll
    for (int r = 0; r < 4; ++r) {
      int c = c0 + r;
      bool ok = act && ((unsigned)(s - c) < 16u);
      int off = ok ? (xrun - r * 16896) : 0;  // clamp to slice base (in-bounds)
      const hf* p = (const hf*)((const char*)xg + off);
      pxc[r][0] = *(const unsigned*)p;
      pxc[r][1] = *(const unsigned*)(p + 2);
      pxc[r][2] = *(const unsigned*)(p + 4);
    }
    xrun += 18432;
  };

  // step (R12 verbatim): zk pins every LDS access after the preceding barrier
  auto step = [&](int acof, int anof, int s, int zk_) -> int {
    const hf* Ac = smem + acof + zk_;
    hf* An = smem + anof + zk_;
    float hcold[4];
#pragma unroll
    for (int r = 0; r < 4; ++r) hcold[r] = (float)Ac[aidx(c0 + r, 128 + d)];
    f32x4 acc[6];
#pragma unroll
    for (int g = 0; g < 6; ++g) acc[g] = (f32x4){0.f, 0.f, 0.f, 0.f};
#pragma unroll
    for (int ks = 0; ks < 8; ++ks) {
      half8 av = *(const half8*)&Ac[aidx(c16, ks * 32 + quad * 8)];
#pragma unroll
      for (int g = 0; g < 5; ++g)
        acc[g] = __builtin_amdgcn_mfma_f32_16x16x32_f16(av, wf[g][ks], acc[g], 0, 0, 0);
      half8 w5 = *(const half8*)&smem[WL_OFF + zk_ + wv * 4096 + ks * 512 + lane * 8];
      acc[5] = __builtin_amdgcn_mfma_f32_16x16x32_f16(av, w5, acc[5], 0, 0, 0);
    }
    if (act) {
#pragma unroll
      for (int r = 0; r < 4; ++r) {
        int c = c0 + r;
        bool okx = ((unsigned)(s - c) < 16u);  // x active window; zero garbage here
        unsigned v0 = okx ? pxc[r][0] : 0u;
        unsigned v1 = okx ? pxc[r][1] : 0u;
        unsigned v2 = okx ? pxc[r][2] : 0u;
        float xur = lo16f(v0), xor_ = hi16f(v0);
        float xir = lo16f(v1), xuc = hi16f(v1);
        float xoc = lo16f(v2), xic = hi16f(v2);
        float uu = sigmoidf_(acc[0][r] + xur);
        float oo = sigmoidf_(acc[1][r] + xor_);
        float ii = tanh_(acc[2][r] + xir);
        float h1 = tanh_(hr[r] + uu * (ii - hr[r])) * oo;
        hr[r] = h1;
        An[aidx(c, d)] = (hf)h1;
        float u2 = sigmoidf_(acc[3][r] + xuc);
        float o2 = sigmoidf_(acc[4][r] + xoc);
        float i2 = tanh_(acc[5][r] + xic);
        float h2 = tanh_(hcold[r] + u2 * (i2 - hcold[r])) * o2;
        int cw = (c == 11) ? 0 : c + 1;  // col roll: h_col[c] feeds slice c+1
        An[aidx(cw, 128 + d)] = (hf)h2;
      }
    }
    xload(s + 1);  // rides across the barrier (wait lands next step)
    return bar_dep();
  };

  xload(0);
  int zk = bar_dep();  // A zero + wlds visible; x loads in flight

#pragma unroll 1
  for (int s = 0; s < Steps - 1; s += 2) {
    zk = step(A0_OFF, A1_OFF, s, zk);
    zk = step(A1_OFF, A0_OFF, s + 1, zk);
  }
  zk = step(A0_OFF, A1_OFF, Steps - 1, zk);  // step 26: A[0] -> A[1]

  // ---- epilogue: h_row[11] at A[1][11][0:128); rolled h_col[11] at A[1][0][128:256) ----
  const hf* Af = smem + A1_OFF + zk;
  float* red = (float*)&smem[H_OFF];  // h dead; alias
  if (t < 128) {
    float hrv = (float)Af[aidx(11, t)];
    float hcv = (float)Af[aidx(0, 128 + t)];
    red[t] = 0.5f * (hcv * fc1_w[cls * 128 + t] + hrv * fc2_w[cls * 128 + t]);
  }
  __syncthreads();
  if (t == 0) {
    float sum = 0.f;
    for (int i = 0; i < 128; ++i) sum += red[i];
    out[bn * 2 + cls] = sum + 0.5f * (fc1_b[cls] + fc2_b[cls]);
  }
}

extern "C" void kernel_launch(void* const* d_in, const int* in_sizes, int n_in,
                              void* d_out, int out_size, void* d_ws, size_t ws_size,
                              hipStream_t stream) {
  const float* x = (const float*)d_in[0];
  // d_in[1] = pad_mask: unused by the reference
  const float* fc3_w = (const float*)d_in[2];
  const float* fc3_b = (const float*)d_in[3];
  const float* fc4_w = (const float*)d_in[4];
  const float* fc4_b = (const float*)d_in[5];
  const float* W_enc = (const float*)d_in[6];
  const float* B_enc = (const float*)d_in[7];
  const float* fc1_w = (const float*)d_in[8];
  const float* fc1_b = (const float*)d_in[9];
  const float* fc2_w = (const float*)d_in[10];
  const float* fc2_b = (const float*)d_in[11];
  float* out = (float*)d_out;

  hf* wsh = (hf*)d_ws;        // frag tables 1,228,800 B
  hf* xWb = wsh + OFF_XW;     // 37,748,736 B (written+read by witran)

  prep<<<dim3(150), dim3(512), 0, stream>>>(fc3_w, fc4_w, W_enc, wsh);
  witran<<<dim3(128), dim3(512), 0, stream>>>(wsh, xWb, x, fc3_b, fc4_b, B_enc,
                                              fc1_w, fc1_b, fc2_w, fc2_b, out);
}

// Round 15
// 157.211 us; speedup vs baseline: 1.4509x; 1.4509x over previous
//
#include <hip/hip_runtime.h>

typedef _Float16 hf;
typedef _Float16 half2v __attribute__((ext_vector_type(2)));
typedef _Float16 half8 __attribute__((ext_vector_type(8)));
typedef float f32x4 __attribute__((ext_vector_type(4)));
typedef int int4v __attribute__((ext_vector_type(4)));

constexpr int Steps = 27;

// ws half-index layout:
//   wrec : [0, 393216)         (((cls*16+wv16)*3+j)*8+ks)*512 + lane*8 + jj
//          wv16<8: row gates {u_r,o_r,i_r}; wv16>=8: col gates {u_c,o_c,i_c}; d=(wv16&7)*16+..
//   wx   : [393216, 589824)    (((cls*6+g)*8+wv)*4+ks)*512 + lane*8 + j   K=[256,384)
//   fc3  : [589824, 598016)
//   fc4  : [598016, 614400)
//   xWb  : [614400, +18874368)  [cls][bn][cell][d*6 + pos], pos: 0,1,2=u_r,o_r,i_r; 3,4,5=u_c,o_c,i_c
constexpr int OFF_WX = 393216;
constexpr int OFF_F3 = 589824;
constexpr int OFF_F4 = 598016;
constexpr int OFF_XW = 614400;

__device__ __forceinline__ int aidx(int r, int k) {  // halfs, K=256 (witran A)
  int blk = k >> 3;
  return r * 256 + (((blk ^ (r & 7)) & 31) << 3) + (k & 7);
}
__device__ __forceinline__ int hidx(int r, int k) {  // halfs, K=128 (prelude h buffers)
  int blk = k >> 3;
  return r * 128 + (((blk ^ (r & 15)) & 15) << 3) + (k & 7);
}
__device__ __forceinline__ int xidx(int r, int k) {  // halfs, K=64 (prelude x)
  int blk = k >> 3;
  return r * 64 + (((blk ^ (r & 7)) & 7) << 3) + (k & 7);
}
// fast transcendentals: v_rcp_f32 instead of IEEE div sequence (~10 instrs each)
__device__ __forceinline__ float rcpf_(float x) { return __builtin_amdgcn_rcpf(x); }
__device__ __forceinline__ float sigmoidf_(float x) { return rcpf_(1.0f + __expf(-x)); }
__device__ __forceinline__ float tanh_(float x) { return 1.0f - 2.0f * rcpf_(__expf(2.0f * x) + 1.0f); }

// Hardened lgkm-only barrier (R12-proven): returns an SGPR zero produced BY the barrier
// asm; post-barrier LDS pointers are offset by it (data dependency = no hoisting), and
// there is NO "memory" clobber (no vmcnt drain; R9's -12us).
__device__ __forceinline__ int bar_dep() {
  int z;
  __builtin_amdgcn_sched_barrier(0);
  asm volatile("s_waitcnt lgkmcnt(0)\n\ts_barrier\n\ts_mov_b32 %0, 0" : "=s"(z));
  __builtin_amdgcn_sched_barrier(0);
  return z;
}

// ---- kernel 1: all weights -> fragment-ordered fp16 (R12 verbatim) ----
__global__ __launch_bounds__(512) void prep(const float* __restrict__ fc3_w,
                                            const float* __restrict__ fc4_w,
                                            const float* __restrict__ W_enc,
                                            hf* __restrict__ wsh) {
  int idx = (blockIdx.x * 512 + threadIdx.x) * 8;  // base of 8-chunk
  if (idx >= OFF_XW) return;
  const float* src;
  if (idx < OFF_WX) {  // recurrent W, gate-triple per wave-block
    int lane = (idx >> 3) & 63, rest = idx >> 9;
    int ks = rest & 7; rest >>= 3;
    int j = rest % 3; rest /= 3;
    int wv = rest & 15, cls = rest >> 4;
    int gate = (wv < 8) ? (j < 2 ? j : 4) : (j < 2 ? j + 2 : 5);  // {0,1,4} / {2,3,5}
    int n = gate * 128 + (wv & 7) * 16 + (lane & 15);
    int k = ks * 32 + ((lane >> 4) << 3);
    src = W_enc + (size_t)(cls * 768 + n) * 384 + k;
  } else if (idx < OFF_F3) {  // x-part Wx
    int f = idx - OFF_WX;
    int lane = (f >> 3) & 63, rest = f >> 9;
    int ks = rest & 3; rest >>= 2;
    int wv = rest & 7; rest >>= 3;
    int gate = rest % 6, cls = rest / 6;
    int n = gate * 128 + wv * 16 + (lane & 15);
    int k = 256 + ks * 32 + ((lane >> 4) << 3);
    src = W_enc + (size_t)(cls * 768 + n) * 384 + k;
  } else if (idx < OFF_F4) {  // fc3
    int f = idx - OFF_F3;
    int lane = (f >> 3) & 63, rest = f >> 9;
    int ks = rest & 1, wv = rest >> 1;
    int n = wv * 16 + (lane & 15), k = ks * 32 + ((lane >> 4) << 3);
    src = fc3_w + n * 64 + k;
  } else {  // fc4
    int f = idx - OFF_F4;
    int lane = (f >> 3) & 63, rest = f >> 9;
    int ks = rest & 3, wv = rest >> 2;
    int n = wv * 16 + (lane & 15), k = ks * 32 + ((lane >> 4) << 3);
    src = fc4_w + n * 128 + k;
  }
  f32x4 a = *(const f32x4*)src, b = *(const f32x4*)(src + 4);
  half8 h;
  h[0] = (hf)a.x; h[1] = (hf)a.y; h[2] = (hf)a.z; h[3] = (hf)a.w;
  h[4] = (hf)b.x; h[5] = (hf)b.y; h[6] = (hf)b.z; h[7] = (hf)b.w;
  *(half8*)&wsh[idx] = h;
}

// ---- kernel 2: frontend MLP + xW precompute. Geometry: 256 blocks x 48 rows
// (was 192 x 64) -- exactly one block per CU, one dispatch round, no idle CUs
// (192 blocks left 25% of the machine idle). 192/48=4: each block stays inside one
// bn slice. Fragment-table reads + MFMA pattern + coalesced store = R12 verbatim
// (mt loop 4 -> 3).
__global__ __launch_bounds__(512) void prelude(
    const float* __restrict__ x, const float* __restrict__ fc3_b, const float* __restrict__ fc4_b,
    const float* __restrict__ B_enc, const hf* __restrict__ wsh, hf* __restrict__ xWb) {
  const int t = threadIdx.x, lane = t & 63, wv = t >> 6;
  const int c16 = lane & 15, quad = lane >> 4;
  const int row0 = blockIdx.x * 48, bn = row0 / 192, l0 = row0 % 192;
  const int d = wv * 16 + c16;

  __shared__ __attribute__((aligned(16))) hf xA[48 * 64];
  __shared__ __attribute__((aligned(16))) hf hbuf[48 * 128];
  __shared__ __attribute__((aligned(16))) hf xout[48 * 768];
  __shared__ float actf[48];

  if (t < 384) {  // stage x -> fp16 swizzled LDS: 48 rows x 64, 8 floats/thread
    int r = t >> 3, cb = (t & 7) * 8;
    const float* xp = x + (size_t)(row0 + r) * 64 + cb;
    f32x4 a = *(const f32x4*)xp, b = *(const f32x4*)(xp + 4);
    half8 h;
    h[0] = (hf)a.x; h[1] = (hf)a.y; h[2] = (hf)a.z; h[3] = (hf)a.w;
    h[4] = (hf)b.x; h[5] = (hf)b.y; h[6] = (hf)b.z; h[7] = (hf)b.w;
    *(half8*)&xA[xidx(r, cb)] = h;
  }
  if (t < 48) {
    int l = l0 + t;
    actf[t] = ((l / 12) + (l % 12)) < 12 ? 1.f : 0.f;
  }
  __syncthreads();

  // fc3 (M=48, K=64)
  {
    float b3v = fc3_b[d];
    half8 w0 = *(const half8*)(wsh + OFF_F3 + (wv * 2 + 0) * 512 + lane * 8);
    half8 w1 = *(const half8*)(wsh + OFF_F3 + (wv * 2 + 1) * 512 + lane * 8);
    f32x4 acc[3] = {{0, 0, 0, 0}, {0, 0, 0, 0}, {0, 0, 0, 0}};
#pragma unroll
    for (int mt = 0; mt < 3; ++mt) {
      half8 a0 = *(const half8*)&xA[xidx(mt * 16 + c16, quad * 8)];
      half8 a1 = *(const half8*)&xA[xidx(mt * 16 + c16, 32 + quad * 8)];
      acc[mt] = __builtin_amdgcn_mfma_f32_16x16x32_f16(a0, w0, acc[mt], 0, 0, 0);
      acc[mt] = __builtin_amdgcn_mfma_f32_16x16x32_f16(a1, w1, acc[mt], 0, 0, 0);
    }
#pragma unroll
    for (int mt = 0; mt < 3; ++mt)
#pragma unroll
      for (int r = 0; r < 4; ++r)
        hbuf[hidx(mt * 16 + quad * 4 + r, d)] = (hf)fmaxf(acc[mt][r] + b3v, 0.f);
  }
  __syncthreads();

  // fc4 (M=48, K=128)
  {
    float b4v = fc4_b[d];
    half8 w4[4];
#pragma unroll
    for (int ks = 0; ks < 4; ++ks)
      w4[ks] = *(const half8*)(wsh + OFF_F4 + (wv * 4 + ks) * 512 + lane * 8);
    f32x4 acc[3] = {{0, 0, 0, 0}, {0, 0, 0, 0}, {0, 0, 0, 0}};
#pragma unroll
    for (int mt = 0; mt < 3; ++mt)
#pragma unroll
      for (int ks = 0; ks < 4; ++ks) {
        half8 a = *(const half8*)&hbuf[hidx(mt * 16 + c16, ks * 32 + quad * 8)];
        acc[mt] = __builtin_amdgcn_mfma_f32_16x16x32_f16(a, w4[ks], acc[mt], 0, 0, 0);
      }
    __syncthreads();
#pragma unroll
    for (int mt = 0; mt < 3; ++mt)
#pragma unroll
      for (int r = 0; r < 4; ++r)
        hbuf[hidx(mt * 16 + quad * 4 + r, d)] = (hf)(acc[mt][r] + b4v);
  }
  __syncthreads();

  // xW: per orig-gate g, store into pos {0,1,3,4,2,5}[g] of the 6-group
  half8 af[3][4];
#pragma unroll
  for (int mt = 0; mt < 3; ++mt)
#pragma unroll
    for (int ks = 0; ks < 4; ++ks)
      af[mt][ks] = *(const half8*)&hbuf[hidx(mt * 16 + c16, ks * 32 + quad * 8)];

  for (int cls = 0; cls < 2; ++cls) {
    for (int g = 0; g < 6; ++g) {
      int pos = (g < 2) ? g : (g < 4 ? g + 1 : (g == 4 ? 2 : 5));
      half8 wf[4];
#pragma unroll
      for (int ks = 0; ks < 4; ++ks)
        wf[ks] = *(const half8*)(wsh + OFF_WX + (((cls * 6 + g) * 8 + wv) * 4 + ks) * 512 + lane * 8);
      float bv = B_enc[cls * 768 + g * 128 + d];
#pragma unroll
      for (int mt = 0; mt < 3; ++mt) {
        f32x4 acc = {0.f, 0.f, 0.f, 0.f};
#pragma unroll
        for (int ks = 0; ks < 4; ++ks)
          acc = __builtin_amdgcn_mfma_f32_16x16x32_f16(af[mt][ks], wf[ks], acc, 0, 0, 0);
#pragma unroll
        for (int r = 0; r < 4; ++r) {
          int row = mt * 16 + quad * 4 + r;
          xout[row * 768 + d * 6 + pos] = (hf)(acc[r] + actf[row] * bv);
        }
      }
    }
    __syncthreads();  // xout complete for this class
    {
      const int* src = (const int*)xout;
      int* dst = (int*)(xWb + (((size_t)cls * 64 + bn) * 192 + l0) * 768);
#pragma unroll
      for (int i = 0; i < 9; ++i) {  // 48*768 halfs = 18432 ints = 512thr x 9 int4
        int base = (t + i * 512) * 4;
        *(int4v*)&dst[base] = *(const int4v*)&src[base];
      }
    }
    __syncthreads();
  }
}

__device__ __forceinline__ float lo16f(unsigned v) {
  return (float)__builtin_bit_cast(half2v, v)[0];
}
__device__ __forceinline__ float hi16f(unsigned v) {
  return (float)__builtin_bit_cast(half2v, v)[1];
}

// ---- kernel 3: recurrence (R12 VERBATIM -- proven 63.7us, race-free hardened barrier).
// 8 waves / 512 threads, owner-computes, 5 weight sets in regs + i_c in wlds.
__global__ __launch_bounds__(512, 2) __attribute__((amdgpu_waves_per_eu(2, 2))) void witran(
    const hf* __restrict__ wsh, const float* __restrict__ fc1_w, const float* __restrict__ fc1_b,
    const float* __restrict__ fc2_w, const float* __restrict__ fc2_b,
    const hf* __restrict__ xWb, float* __restrict__ out) {
  const int cls = blockIdx.x & 1, bn = blockIdx.x >> 1;
  const int t = threadIdx.x, lane = t & 63, wv = t >> 6;  // wv 0..7
  const int c16 = lane & 15, quad = lane >> 4;
  const int d = wv * 16 + c16;
  const bool act = (quad < 3);
  const int c0 = quad * 4;

  __shared__ __attribute__((aligned(16))) hf wlds[8 * 4096];  // i_c set, 8KB/wave
  __shared__ __attribute__((aligned(16))) hf A[2][4096];      // double buffer
  __shared__ float red[128];

  for (int i = t; i < 4096; i += 512) ((int*)A)[i] = 0;  // zero both buffers

  // weights: wf[0..2]=u_r,o_r,i_r (row triple, block cls*16+wv);
  //          wf[3..4]=u_c,o_c (col triple j=0,1, block cls*16+8+wv); i_c (j=2) -> wlds
  half8 wf[5][8];
  {
    const hf* wbR = wsh + ((size_t)((cls * 16 + wv) * 3) * 8) * 512 + lane * 8;
    const hf* wbC = wsh + ((size_t)((cls * 16 + 8 + wv) * 3) * 8) * 512 + lane * 8;
#pragma unroll
    for (int j = 0; j < 3; ++j)
#pragma unroll
      for (int ks = 0; ks < 8; ++ks)
        wf[j][ks] = *(const half8*)(wbR + (j * 8 + ks) * 512);
#pragma unroll
    for (int j = 0; j < 2; ++j)
#pragma unroll
      for (int ks = 0; ks < 8; ++ks)
        wf[3 + j][ks] = *(const half8*)(wbC + (j * 8 + ks) * 512);
#pragma unroll
    for (int ks = 0; ks < 8; ++ks)
      *(half8*)&wlds[wv * 4096 + ks * 512 + lane * 8] = *(const half8*)(wbC + (16 + ks) * 512);
  }

  const hf* xg = xWb + ((size_t)cls * 64 + bn) * 192 * 768;
  // x byte-offset for cell (rr=s-c, c), this lane's d:
  //   off(s,c) = s*18432 - c*16896 + d*12 ;  xrun tracks s*18432 - c0*16896 + d*12
  int xrun = d * 12 - c0 * 16896;
  unsigned pxc[4][3];
  float hr[4] = {0.f, 0.f, 0.f, 0.f};  // row holds: self-owned, registers

  auto xload = [&](int s) {  // prefetch x-gates for step s; RAW values, no select on data
#pragma unroll
    for (int r = 0; r < 4; ++r) {
      int c = c0 + r;
      bool ok = act && ((unsigned)(s - c) < 16u);
      int off = ok ? (xrun - r * 16896) : 0;  // clamp to block base (in-bounds)
      const hf* p = (const hf*)((const char*)xg + off);
      pxc[r][0] = *(const unsigned*)p;
      pxc[r][1] = *(const unsigned*)(p + 2);
      pxc[r][2] = *(const unsigned*)(p + 4);
    }
    xrun += 18432;
  };

  // step: Ac0/An0 are raw buffer pointers; zk is the barrier-produced zero that pins
  // every LDS access of this step AFTER the preceding barrier. Returns next zk.
  auto step = [&](const hf* Ac0, hf* An0, int s, int zk) -> int {
    const hf* Ac = Ac0 + zk;
    hf* An = An0 + zk;
    // col holds from current state (issued first; latency hides under the GEMM)
    float hcold[4];
#pragma unroll
    for (int r = 0; r < 4; ++r) hcold[r] = (float)Ac[aidx(c0 + r, 128 + d)];
    // ---- GEMM: 6 gates x K=256; 5 weight sets in regs, i_c from wlds ----
    f32x4 acc[6];
#pragma unroll
    for (int g = 0; g < 6; ++g) acc[g] = (f32x4){0.f, 0.f, 0.f, 0.f};
#pragma unroll
    for (int ks = 0; ks < 8; ++ks) {
      half8 av = *(const half8*)&Ac[aidx(c16, ks * 32 + quad * 8)];
#pragma unroll
      for (int g = 0; g < 5; ++g)
        acc[g] = __builtin_amdgcn_mfma_f32_16x16x32_f16(av, wf[g][ks], acc[g], 0, 0, 0);
      half8 w5 = *(const half8*)&wlds[zk + wv * 4096 + ks * 512 + lane * 8];
      acc[5] = __builtin_amdgcn_mfma_f32_16x16x32_f16(av, w5, acc[5], 0, 0, 0);
    }
    // ---- owner update: 4 cells x {row, col}; okx select at USE site ----
    if (act) {
#pragma unroll
      for (int r = 0; r < 4; ++r) {
        int c = c0 + r;
        bool okx = ((unsigned)(s - c) < 16u);  // x active window; zero garbage here
        unsigned v0 = okx ? pxc[r][0] : 0u;
        unsigned v1 = okx ? pxc[r][1] : 0u;
        unsigned v2 = okx ? pxc[r][2] : 0u;
        float xur = lo16f(v0), xor_ = hi16f(v0);
        float xir = lo16f(v1), xuc = hi16f(v1);
        float xoc = lo16f(v2), xic = hi16f(v2);
        float uu = sigmoidf_(acc[0][r] + xur);
        float oo = sigmoidf_(acc[1][r] + xor_);
        float ii = tanh_(acc[2][r] + xir);
        float h1 = tanh_(hr[r] + uu * (ii - hr[r])) * oo;
        hr[r] = h1;
        An[aidx(c, d)] = (hf)h1;
        float u2 = sigmoidf_(acc[3][r] + xuc);
        float o2 = sigmoidf_(acc[4][r] + xoc);
        float i2 = tanh_(acc[5][r] + xic);
        float h2 = tanh_(hcold[r] + u2 * (i2 - hcold[r])) * o2;
        int cw = (c == 11) ? 0 : c + 1;  // col roll: h_col[c] feeds slice c+1
        An[aidx(cw, 128 + d)] = (hf)h2;
      }
    }
    // prefetch next step's x-gates; loads ride across the barrier (wait lands next step)
    xload(s + 1);
    return bar_dep();  // An complete; all Ac reads retired (lgkm only; vmcnt in flight)
  };

  xload(0);
  int zk = bar_dep();  // A zero + wlds visible; x loads in flight

#pragma unroll 1
  for (int s = 0; s < Steps - 1; s += 2) {
    zk = step(A[0], A[1], s, zk);
    zk = step(A[1], A[0], s + 1, zk);
  }
  zk = step(A[0], A[1], Steps - 1, zk);  // step 26: A[0] -> A[1]

  // ---- epilogue: h_row[11] at A[1][11][0:128); rolled h_col[11] at A[1][0][128:256) ----
  const hf* Af = A[1] + zk;  // zk pins epilogue reads after the final barrier
  if (t < 128) {
    float hrv = (float)Af[aidx(11, t)];
    float hcv = (float)Af[aidx(0, 128 + t)];
    red[t] = 0.5f * (hcv * fc1_w[cls * 128 + t] + hrv * fc2_w[cls * 128 + t]);
  }
  __syncthreads();
  if (t == 0) {
    float sum = 0.f;
    for (int i = 0; i < 128; ++i) sum += red[i];
    out[bn * 2 + cls] = sum + 0.5f * (fc1_b[cls] + fc2_b[cls]);
  }
}

extern "C" void kernel_launch(void* const* d_in, const int* in_sizes, int n_in,
                              void* d_out, int out_size, void* d_ws, size_t ws_size,
                              hipStream_t stream) {
  const float* x = (const float*)d_in[0];
  // d_in[1] = pad_mask: unused by the reference
  const float* fc3_w = (const float*)d_in[2];
  const float* fc3_b = (const float*)d_in[3];
  const float* fc4_w = (const float*)d_in[4];
  const float* fc4_b = (const float*)d_in[5];
  const float* W_enc = (const float*)d_in[6];
  const float* B_enc = (const float*)d_in[7];
  const float* fc1_w = (const float*)d_in[8];
  const float* fc1_b = (const float*)d_in[9];
  const float* fc2_w = (const float*)d_in[10];
  const float* fc2_b = (const float*)d_in[11];
  float* out = (float*)d_out;

  hf* wsh = (hf*)d_ws;        // frag tables 1,228,800 B
  hf* xWb = wsh + OFF_XW;     // 37,748,736 B ; total 38,977,536 B

  prep<<<dim3(150), dim3(512), 0, stream>>>(fc3_w, fc4_w, W_enc, wsh);
  prelude<<<dim3(256), dim3(512), 0, stream>>>(x, fc3_b, fc4_b, B_enc, wsh, xWb);
  witran<<<dim3(128), dim3(512), 0, stream>>>(wsh, fc1_w, fc1_b, fc2_w, fc2_b, xWb, out);
}

// Round 16
// 156.313 us; speedup vs baseline: 1.4593x; 1.0057x over previous
//
#include <hip/hip_runtime.h>

typedef _Float16 hf;
typedef _Float16 half2v __attribute__((ext_vector_type(2)));
typedef _Float16 half8 __attribute__((ext_vector_type(8)));
typedef float f32x4 __attribute__((ext_vector_type(4)));
typedef int int4v __attribute__((ext_vector_type(4)));

constexpr int Steps = 27;

// ws half-index layout:
//   wrec : [0, 393216)         (((cls*16+wv16)*3+j)*8+ks)*512 + lane*8 + jj
//          wv16<8: row gates {u_r,o_r,i_r}; wv16>=8: col gates {u_c,o_c,i_c}; d=(wv16&7)*16+..
//   wx   : [393216, 589824)    (((cls*6+g)*8+wv)*4+ks)*512 + lane*8 + j   K=[256,384)
//   fc3  : [589824, 598016)
//   fc4  : [598016, 614400)
//   xWb  : [614400, +18874368)  [cls][bn][cell][d*6 + pos], pos: 0,1,2=u_r,o_r,i_r; 3,4,5=u_c,o_c,i_c
constexpr int OFF_WX = 393216;
constexpr int OFF_F3 = 589824;
constexpr int OFF_F4 = 598016;
constexpr int OFF_XW = 614400;

__device__ __forceinline__ int aidx(int r, int k) {  // halfs, K=256 (witran A)
  int blk = k >> 3;
  return r * 256 + (((blk ^ (r & 7)) & 31) << 3) + (k & 7);
}
__device__ __forceinline__ int hidx(int r, int k) {  // halfs, K=128 (prelude h buffers)
  int blk = k >> 3;
  return r * 128 + (((blk ^ (r & 15)) & 15) << 3) + (k & 7);
}
__device__ __forceinline__ int xidx(int r, int k) {  // halfs, K=64 (prelude x)
  int blk = k >> 3;
  return r * 64 + (((blk ^ (r & 7)) & 7) << 3) + (k & 7);
}
// fast transcendentals: v_rcp_f32 instead of IEEE div sequence (~10 instrs each)
__device__ __forceinline__ float rcpf_(float x) { return __builtin_amdgcn_rcpf(x); }
__device__ __forceinline__ float sigmoidf_(float x) { return rcpf_(1.0f + __expf(-x)); }
__device__ __forceinline__ float tanh_(float x) { return 1.0f - 2.0f * rcpf_(__expf(2.0f * x) + 1.0f); }

// Hardened lgkm-only barrier (R12-proven): returns an SGPR zero produced BY the barrier
// asm; post-barrier LDS pointers are offset by it (data dependency = no hoisting), and
// there is NO "memory" clobber (no vmcnt drain; R9's -12us).
__device__ __forceinline__ int bar_dep() {
  int z;
  __builtin_amdgcn_sched_barrier(0);
  asm volatile("s_waitcnt lgkmcnt(0)\n\ts_barrier\n\ts_mov_b32 %0, 0" : "=s"(z));
  __builtin_amdgcn_sched_barrier(0);
  return z;
}

// ---- kernel 1: all weights -> fragment-ordered fp16 (R12 verbatim) ----
__global__ __launch_bounds__(512) void prep(const float* __restrict__ fc3_w,
                                            const float* __restrict__ fc4_w,
                                            const float* __restrict__ W_enc,
                                            hf* __restrict__ wsh) {
  int idx = (blockIdx.x * 512 + threadIdx.x) * 8;  // base of 8-chunk
  if (idx >= OFF_XW) return;
  const float* src;
  if (idx < OFF_WX) {  // recurrent W, gate-triple per wave-block
    int lane = (idx >> 3) & 63, rest = idx >> 9;
    int ks = rest & 7; rest >>= 3;
    int j = rest % 3; rest /= 3;
    int wv = rest & 15, cls = rest >> 4;
    int gate = (wv < 8) ? (j < 2 ? j : 4) : (j < 2 ? j + 2 : 5);  // {0,1,4} / {2,3,5}
    int n = gate * 128 + (wv & 7) * 16 + (lane & 15);
    int k = ks * 32 + ((lane >> 4) << 3);
    src = W_enc + (size_t)(cls * 768 + n) * 384 + k;
  } else if (idx < OFF_F3) {  // x-part Wx
    int f = idx - OFF_WX;
    int lane = (f >> 3) & 63, rest = f >> 9;
    int ks = rest & 3; rest >>= 2;
    int wv = rest & 7; rest >>= 3;
    int gate = rest % 6, cls = rest / 6;
    int n = gate * 128 + wv * 16 + (lane & 15);
    int k = 256 + ks * 32 + ((lane >> 4) << 3);
    src = W_enc + (size_t)(cls * 768 + n) * 384 + k;
  } else if (idx < OFF_F4) {  // fc3
    int f = idx - OFF_F3;
    int lane = (f >> 3) & 63, rest = f >> 9;
    int ks = rest & 1, wv = rest >> 1;
    int n = wv * 16 + (lane & 15), k = ks * 32 + ((lane >> 4) << 3);
    src = fc3_w + n * 64 + k;
  } else {  // fc4
    int f = idx - OFF_F4;
    int lane = (f >> 3) & 63, rest = f >> 9;
    int ks = rest & 3, wv = rest >> 2;
    int n = wv * 16 + (lane & 15), k = ks * 32 + ((lane >> 4) << 3);
    src = fc4_w + n * 128 + k;
  }
  f32x4 a = *(const f32x4*)src, b = *(const f32x4*)(src + 4);
  half8 h;
  h[0] = (hf)a.x; h[1] = (hf)a.y; h[2] = (hf)a.z; h[3] = (hf)a.w;
  h[4] = (hf)b.x; h[5] = (hf)b.y; h[6] = (hf)b.z; h[7] = (hf)b.w;
  *(half8*)&wsh[idx] = h;
}

// ---- kernel 2: frontend MLP + xW precompute; 256 blocks x 48 rows (R15 geometry).
// xW phase restructured: all 6 gate accumulators computed per mt BEFORE writing, so
// each (row,d) emits its 12 contiguous bytes as 3 ds_write_b32 (was 6x2 scattered
// u16 across the g loop) -- halves xW LDS ops, 6-way MFMA ILP. wf6[6][4] = 96 VGPR
// resident per cls => pin waves_per_eu(2,2) for the 256-reg budget (prelude already
// runs 1 block/CU at 91KB LDS, so pinning costs no occupancy).
__global__ __launch_bounds__(512, 2) __attribute__((amdgpu_waves_per_eu(2, 2))) void prelude(
    const float* __restrict__ x, const float* __restrict__ fc3_b, const float* __restrict__ fc4_b,
    const float* __restrict__ B_enc, const hf* __restrict__ wsh, hf* __restrict__ xWb) {
  const int t = threadIdx.x, lane = t & 63, wv = t >> 6;
  const int c16 = lane & 15, quad = lane >> 4;
  const int row0 = blockIdx.x * 48, bn = row0 / 192, l0 = row0 % 192;
  const int d = wv * 16 + c16;

  __shared__ __attribute__((aligned(16))) hf xA[48 * 64];
  __shared__ __attribute__((aligned(16))) hf hbuf[48 * 128];
  __shared__ __attribute__((aligned(16))) hf xout[48 * 768];
  __shared__ float actf[48];

  if (t < 384) {  // stage x -> fp16 swizzled LDS: 48 rows x 64, 8 floats/thread
    int r = t >> 3, cb = (t & 7) * 8;
    const float* xp = x + (size_t)(row0 + r) * 64 + cb;
    f32x4 a = *(const f32x4*)xp, b = *(const f32x4*)(xp + 4);
    half8 h;
    h[0] = (hf)a.x; h[1] = (hf)a.y; h[2] = (hf)a.z; h[3] = (hf)a.w;
    h[4] = (hf)b.x; h[5] = (hf)b.y; h[6] = (hf)b.z; h[7] = (hf)b.w;
    *(half8*)&xA[xidx(r, cb)] = h;
  }
  if (t < 48) {
    int l = l0 + t;
    actf[t] = ((l / 12) + (l % 12)) < 12 ? 1.f : 0.f;
  }
  __syncthreads();

  // fc3 (M=48, K=64)
  {
    float b3v = fc3_b[d];
    half8 w0 = *(const half8*)(wsh + OFF_F3 + (wv * 2 + 0) * 512 + lane * 8);
    half8 w1 = *(const half8*)(wsh + OFF_F3 + (wv * 2 + 1) * 512 + lane * 8);
    f32x4 acc[3] = {{0, 0, 0, 0}, {0, 0, 0, 0}, {0, 0, 0, 0}};
#pragma unroll
    for (int mt = 0; mt < 3; ++mt) {
      half8 a0 = *(const half8*)&xA[xidx(mt * 16 + c16, quad * 8)];
      half8 a1 = *(const half8*)&xA[xidx(mt * 16 + c16, 32 + quad * 8)];
      acc[mt] = __builtin_amdgcn_mfma_f32_16x16x32_f16(a0, w0, acc[mt], 0, 0, 0);
      acc[mt] = __builtin_amdgcn_mfma_f32_16x16x32_f16(a1, w1, acc[mt], 0, 0, 0);
    }
#pragma unroll
    for (int mt = 0; mt < 3; ++mt)
#pragma unroll
      for (int r = 0; r < 4; ++r)
        hbuf[hidx(mt * 16 + quad * 4 + r, d)] = (hf)fmaxf(acc[mt][r] + b3v, 0.f);
  }
  __syncthreads();

  // fc4 (M=48, K=128)
  {
    float b4v = fc4_b[d];
    half8 w4[4];
#pragma unroll
    for (int ks = 0; ks < 4; ++ks)
      w4[ks] = *(const half8*)(wsh + OFF_F4 + (wv * 4 + ks) * 512 + lane * 8);
    f32x4 acc[3] = {{0, 0, 0, 0}, {0, 0, 0, 0}, {0, 0, 0, 0}};
#pragma unroll
    for (int mt = 0; mt < 3; ++mt)
#pragma unroll
      for (int ks = 0; ks < 4; ++ks) {
        half8 a = *(const half8*)&hbuf[hidx(mt * 16 + c16, ks * 32 + quad * 8)];
        acc[mt] = __builtin_amdgcn_mfma_f32_16x16x32_f16(a, w4[ks], acc[mt], 0, 0, 0);
      }
    __syncthreads();
#pragma unroll
    for (int mt = 0; mt < 3; ++mt)
#pragma unroll
      for (int r = 0; r < 4; ++r)
        hbuf[hidx(mt * 16 + quad * 4 + r, d)] = (hf)(acc[mt][r] + b4v);
  }
  __syncthreads();

  // xW: all 6 gates per mt, packed 12B-contiguous writes (pos order {g0,g1,g4,g2,g3,g5})
  half8 af[3][4];
#pragma unroll
  for (int mt = 0; mt < 3; ++mt)
#pragma unroll
    for (int ks = 0; ks < 4; ++ks)
      af[mt][ks] = *(const half8*)&hbuf[hidx(mt * 16 + c16, ks * 32 + quad * 8)];

  for (int cls = 0; cls < 2; ++cls) {
    half8 wf6[6][4];
    float bv6[6];
#pragma unroll
    for (int g = 0; g < 6; ++g) {
#pragma unroll
      for (int ks = 0; ks < 4; ++ks)
        wf6[g][ks] =
            *(const half8*)(wsh + OFF_WX + (((cls * 6 + g) * 8 + wv) * 4 + ks) * 512 + lane * 8);
      bv6[g] = B_enc[cls * 768 + g * 128 + d];
    }
#pragma unroll
    for (int mt = 0; mt < 3; ++mt) {
      f32x4 a6[6];
#pragma unroll
      for (int g = 0; g < 6; ++g) a6[g] = (f32x4){0.f, 0.f, 0.f, 0.f};
#pragma unroll
      for (int ks = 0; ks < 4; ++ks)
#pragma unroll
        for (int g = 0; g < 6; ++g)
          a6[g] = __builtin_amdgcn_mfma_f32_16x16x32_f16(af[mt][ks], wf6[g][ks], a6[g], 0, 0, 0);
#pragma unroll
      for (int r = 0; r < 4; ++r) {
        int row = mt * 16 + quad * 4 + r;
        float am = actf[row];
        float v0 = a6[0][r] + am * bv6[0];
        float v1 = a6[1][r] + am * bv6[1];
        float v2 = a6[2][r] + am * bv6[2];
        float v3 = a6[3][r] + am * bv6[3];
        float v4 = a6[4][r] + am * bv6[4];
        float v5 = a6[5][r] + am * bv6[5];
        half2v p0; p0[0] = (hf)v0; p0[1] = (hf)v1;  // pos 0,1 = g0,g1
        half2v p1; p1[0] = (hf)v4; p1[1] = (hf)v2;  // pos 2,3 = g4,g2
        half2v p2; p2[0] = (hf)v3; p2[1] = (hf)v5;  // pos 4,5 = g3,g5
        int* xo = (int*)xout + row * 384 + d * 3;   // 12B-aligned (12d % 4 == 0)
        xo[0] = __builtin_bit_cast(int, p0);
        xo[1] = __builtin_bit_cast(int, p1);
        xo[2] = __builtin_bit_cast(int, p2);
      }
    }
    __syncthreads();  // xout complete for this class
    {
      const int* src = (const int*)xout;
      int* dst = (int*)(xWb + (((size_t)cls * 64 + bn) * 192 + l0) * 768);
#pragma unroll
      for (int i = 0; i < 9; ++i) {  // 48*768 halfs = 18432 ints = 512thr x 9 int4
        int base = (t + i * 512) * 4;
        *(int4v*)&dst[base] = *(const int4v*)&src[base];
      }
    }
    __syncthreads();
  }
}

__device__ __forceinline__ float lo16f(unsigned v) {
  return (float)__builtin_bit_cast(half2v, v)[0];
}
__device__ __forceinline__ float hi16f(unsigned v) {
  return (float)__builtin_bit_cast(half2v, v)[1];
}

// ---- kernel 3: recurrence (R12 VERBATIM -- proven 62-64us, race-free hardened barrier).
// 8 waves / 512 threads, owner-computes, 5 weight sets in regs + i_c in wlds.
__global__ __launch_bounds__(512, 2) __attribute__((amdgpu_waves_per_eu(2, 2))) void witran(
    const hf* __restrict__ wsh, const float* __restrict__ fc1_w, const float* __restrict__ fc1_b,
    const float* __restrict__ fc2_w, const float* __restrict__ fc2_b,
    const hf* __restrict__ xWb, float* __restrict__ out) {
  const int cls = blockIdx.x & 1, bn = blockIdx.x >> 1;
  const int t = threadIdx.x, lane = t & 63, wv = t >> 6;  // wv 0..7
  const int c16 = lane & 15, quad = lane >> 4;
  const int d = wv * 16 + c16;
  const bool act = (quad < 3);
  const int c0 = quad * 4;

  __shared__ __attribute__((aligned(16))) hf wlds[8 * 4096];  // i_c set, 8KB/wave
  __shared__ __attribute__((aligned(16))) hf A[2][4096];      // double buffer
  __shared__ float red[128];

  for (int i = t; i < 4096; i += 512) ((int*)A)[i] = 0;  // zero both buffers

  // weights: wf[0..2]=u_r,o_r,i_r (row triple, block cls*16+wv);
  //          wf[3..4]=u_c,o_c (col triple j=0,1, block cls*16+8+wv); i_c (j=2) -> wlds
  half8 wf[5][8];
  {
    const hf* wbR = wsh + ((size_t)((cls * 16 + wv) * 3) * 8) * 512 + lane * 8;
    const hf* wbC = wsh + ((size_t)((cls * 16 + 8 + wv) * 3) * 8) * 512 + lane * 8;
#pragma unroll
    for (int j = 0; j < 3; ++j)
#pragma unroll
      for (int ks = 0; ks < 8; ++ks)
        wf[j][ks] = *(const half8*)(wbR + (j * 8 + ks) * 512);
#pragma unroll
    for (int j = 0; j < 2; ++j)
#pragma unroll
      for (int ks = 0; ks < 8; ++ks)
        wf[3 + j][ks] = *(const half8*)(wbC + (j * 8 + ks) * 512);
#pragma unroll
    for (int ks = 0; ks < 8; ++ks)
      *(half8*)&wlds[wv * 4096 + ks * 512 + lane * 8] = *(const half8*)(wbC + (16 + ks) * 512);
  }

  const hf* xg = xWb + ((size_t)cls * 64 + bn) * 192 * 768;
  // x byte-offset for cell (rr=s-c, c), this lane's d:
  //   off(s,c) = s*18432 - c*16896 + d*12 ;  xrun tracks s*18432 - c0*16896 + d*12
  int xrun = d * 12 - c0 * 16896;
  unsigned pxc[4][3];
  float hr[4] = {0.f, 0.f, 0.f, 0.f};  // row holds: self-owned, registers

  auto xload = [&](int s) {  // prefetch x-gates for step s; RAW values, no select on data
#pragma unroll
    for (int r = 0; r < 4; ++r) {
      int c = c0 + r;
      bool ok = act && ((unsigned)(s - c) < 16u);
      int off = ok ? (xrun - r * 16896) : 0;  // clamp to block base (in-bounds)
      const hf* p = (const hf*)((const char*)xg + off);
      pxc[r][0] = *(const unsigned*)p;
      pxc[r][1] = *(const unsigned*)(p + 2);
      pxc[r][2] = *(const unsigned*)(p + 4);
    }
    xrun += 18432;
  };

  // step: Ac0/An0 are raw buffer pointers; zk is the barrier-produced zero that pins
  // every LDS access of this step AFTER the preceding barrier. Returns next zk.
  auto step = [&](const hf* Ac0, hf* An0, int s, int zk) -> int {
    const hf* Ac = Ac0 + zk;
    hf* An = An0 + zk;
    // col holds from current state (issued first; latency hides under the GEMM)
    float hcold[4];
#pragma unroll
    for (int r = 0; r < 4; ++r) hcold[r] = (float)Ac[aidx(c0 + r, 128 + d)];
    // ---- GEMM: 6 gates x K=256; 5 weight sets in regs, i_c from wlds ----
    f32x4 acc[6];
#pragma unroll
    for (int g = 0; g < 6; ++g) acc[g] = (f32x4){0.f, 0.f, 0.f, 0.f};
#pragma unroll
    for (int ks = 0; ks < 8; ++ks) {
      half8 av = *(const half8*)&Ac[aidx(c16, ks * 32 + quad * 8)];
#pragma unroll
      for (int g = 0; g < 5; ++g)
        acc[g] = __builtin_amdgcn_mfma_f32_16x16x32_f16(av, wf[g][ks], acc[g], 0, 0, 0);
      half8 w5 = *(const half8*)&wlds[zk + wv * 4096 + ks * 512 + lane * 8];
      acc[5] = __builtin_amdgcn_mfma_f32_16x16x32_f16(av, w5, acc[5], 0, 0, 0);
    }
    // ---- owner update: 4 cells x {row, col}; okx select at USE site ----
    if (act) {
#pragma unroll
      for (int r = 0; r < 4; ++r) {
        int c = c0 + r;
        bool okx = ((unsigned)(s - c) < 16u);  // x active window; zero garbage here
        unsigned v0 = okx ? pxc[r][0] : 0u;
        unsigned v1 = okx ? pxc[r][1] : 0u;
        unsigned v2 = okx ? pxc[r][2] : 0u;
        float xur = lo16f(v0), xor_ = hi16f(v0);
        float xir = lo16f(v1), xuc = hi16f(v1);
        float xoc = lo16f(v2), xic = hi16f(v2);
        float uu = sigmoidf_(acc[0][r] + xur);
        float oo = sigmoidf_(acc[1][r] + xor_);
        float ii = tanh_(acc[2][r] + xir);
        float h1 = tanh_(hr[r] + uu * (ii - hr[r])) * oo;
        hr[r] = h1;
        An[aidx(c, d)] = (hf)h1;
        float u2 = sigmoidf_(acc[3][r] + xuc);
        float o2 = sigmoidf_(acc[4][r] + xoc);
        float i2 = tanh_(acc[5][r] + xic);
        float h2 = tanh_(hcold[r] + u2 * (i2 - hcold[r])) * o2;
        int cw = (c == 11) ? 0 : c + 1;  // col roll: h_col[c] feeds slice c+1
        An[aidx(cw, 128 + d)] = (hf)h2;
      }
    }
    // prefetch next step's x-gates; loads ride across the barrier (wait lands next step)
    xload(s + 1);
    return bar_dep();  // An complete; all Ac reads retired (lgkm only; vmcnt in flight)
  };

  xload(0);
  int zk = bar_dep();  // A zero + wlds visible; x loads in flight

#pragma unroll 1
  for (int s = 0; s < Steps - 1; s += 2) {
    zk = step(A[0], A[1], s, zk);
    zk = step(A[1], A[0], s + 1, zk);
  }
  zk = step(A[0], A[1], Steps - 1, zk);  // step 26: A[0] -> A[1]

  // ---- epilogue: h_row[11] at A[1][11][0:128); rolled h_col[11] at A[1][0][128:256) ----
  const hf* Af = A[1] + zk;  // zk pins epilogue reads after the final barrier
  if (t < 128) {
    float hrv = (float)Af[aidx(11, t)];
    float hcv = (float)Af[aidx(0, 128 + t)];
    red[t] = 0.5f * (hcv * fc1_w[cls * 128 + t] + hrv * fc2_w[cls * 128 + t]);
  }
  __syncthreads();
  if (t == 0) {
    float sum = 0.f;
    for (int i = 0; i < 128; ++i) sum += red[i];
    out[bn * 2 + cls] = sum + 0.5f * (fc1_b[cls] + fc2_b[cls]);
  }
}

extern "C" void kernel_launch(void* const* d_in, const int* in_sizes, int n_in,
                              void* d_out, int out_size, void* d_ws, size_t ws_size,
                              hipStream_t stream) {
  const float* x = (const float*)d_in[0];
  // d_in[1] = pad_mask: unused by the reference
  const float* fc3_w = (const float*)d_in[2];
  const float* fc3_b = (const float*)d_in[3];
  const float* fc4_w = (const float*)d_in[4];
  const float* fc4_b = (const float*)d_in[5];
  const float* W_enc = (const float*)d_in[6];
  const float* B_enc = (const float*)d_in[7];
  const float* fc1_w = (const float*)d_in[8];
  const float* fc1_b = (const float*)d_in[9];
  const float* fc2_w = (const float*)d_in[10];
  const float* fc2_b = (const float*)d_in[11];
  float* out = (float*)d_out;

  hf* wsh = (hf*)d_ws;        // frag tables 1,228,800 B
  hf* xWb = wsh + OFF_XW;     // 37,748,736 B ; total 38,977,536 B

  prep<<<dim3(150), dim3(512), 0, stream>>>(fc3_w, fc4_w, W_enc, wsh);
  prelude<<<dim3(256), dim3(512), 0, stream>>>(x, fc3_b, fc4_b, B_enc, wsh, xWb);
  witran<<<dim3(128), dim3(512), 0, stream>>>(wsh, fc1_w, fc1_b, fc2_w, fc2_b, xWb, out);
}